// Round 13
// baseline (143.592 us; speedup 1.0000x reference)
//
#include <hip/hip_runtime.h>

#define N_TOT 8192
#define SEQ_L 512
#define D 128
#define NCHUNK 16
#define CHUNK (N_TOT / NCHUNK)   // 512 cols per j-chunk == one seq block
#define NJT_H 4                  // 4 x 64-col tiles per half-chunk
#define NDIAG 272                // 256 pos-blocks + 16 seq-end blocks
#define LOG2E 1.4426950408889634f
#define LN2   0.6931471805599453f

using bf16x8  = __attribute__((ext_vector_type(8))) short;
using f32x4   = __attribute__((ext_vector_type(4))) float;

static __device__ __forceinline__ unsigned short f2bf(float f) {
    unsigned int u = __float_as_uint(f);
    u = (u + 0x7FFFu + ((u >> 16) & 1u)) >> 16;
    return (unsigned short)u;
}
static __device__ __forceinline__ float bf2f(unsigned short h) {
    return __uint_as_float(((unsigned int)h) << 16);
}
static __device__ __forceinline__ float dot8(bf16x8 a, bf16x8 b) {
    float s = 0.f;
    #pragma unroll
    for (int k = 0; k < 8; ++k)
        s = fmaf(bf2f((unsigned short)a[k]), bf2f((unsigned short)b[k]), s);
    return s;
}

// ---------------- one-shot: convert w1/w2 to bf16 ----------------
__global__ __launch_bounds__(256) void convert_w_kernel(
    const float* __restrict__ w1, const float* __restrict__ w2,
    unsigned short* __restrict__ w1b, unsigned short* __restrict__ w2b)
{
    int idx = blockIdx.x * 256 + threadIdx.x;
    const float* src = (idx < 8192) ? w1 : w2;
    unsigned short* dst = (idx < 8192) ? w1b : w2b;
    int off = ((idx < 8192) ? idx : idx - 8192) * 4;
    float4 v = *(const float4*)(src + off);
    ushort4 o;
    o.x = f2bf(v.x); o.y = f2bf(v.y); o.z = f2bf(v.z); o.w = f2bf(v.w);
    *(ushort4*)(dst + off) = o;
}

// ---------------- MFMA MLP (32 rows/block) + fused BN column partials ----------------
__global__ __launch_bounds__(256) void mlp_mfma_kernel(
    const float* __restrict__ x1, const float* __restrict__ x2,
    const unsigned short* __restrict__ w1b, const float* __restrict__ b1,
    const unsigned short* __restrict__ w2b, const float* __restrict__ b2,
    unsigned short* __restrict__ z1, unsigned short* __restrict__ z2,
    float* __restrict__ part_s, float* __restrict__ part_ss)
{
    __shared__ unsigned short hsh[32][264];
    const int t = threadIdx.x;
    const int w = t >> 6;
    const int lane = t & 63;
    const int g = lane >> 4;
    const int c16 = lane & 15;
    const int tensor = blockIdx.x >> 8;
    const int blk = blockIdx.x & 255;
    const int r0 = blk * 32;
    const float* __restrict__ x = tensor ? x2 : x1;
    unsigned short* __restrict__ z = tensor ? z2 : z1;

    // ---- layer 1 ----
    bf16x8 af[2][4];
    #pragma unroll
    for (int rf = 0; rf < 2; ++rf)
        #pragma unroll
        for (int ks = 0; ks < 4; ++ks) {
            const float* xp = x + (size_t)(r0 + rf * 16 + c16) * D + ks * 32 + g * 8;
            float4 u0 = *(const float4*)xp;
            float4 u1 = *(const float4*)(xp + 4);
            bf16x8 a;
            a[0] = f2bf(u0.x); a[1] = f2bf(u0.y); a[2] = f2bf(u0.z); a[3] = f2bf(u0.w);
            a[4] = f2bf(u1.x); a[5] = f2bf(u1.y); a[6] = f2bf(u1.z); a[7] = f2bf(u1.w);
            af[rf][ks] = a;
        }
    f32x4 acc1[2][4] = {};
    #pragma unroll
    for (int ks = 0; ks < 4; ++ks)
        #pragma unroll
        for (int nf = 0; nf < 4; ++nf) {
            int n = w * 64 + nf * 16 + c16;
            bf16x8 b = *(const bf16x8*)(w1b + (size_t)n * D + ks * 32 + g * 8);
            #pragma unroll
            for (int rf = 0; rf < 2; ++rf)
                acc1[rf][nf] = __builtin_amdgcn_mfma_f32_16x16x32_bf16(af[rf][ks], b, acc1[rf][nf], 0, 0, 0);
        }
    #pragma unroll
    for (int nf = 0; nf < 4; ++nf) {
        float bb = b1[w * 64 + nf * 16 + c16];
        #pragma unroll
        for (int rf = 0; rf < 2; ++rf)
            #pragma unroll
            for (int r = 0; r < 4; ++r)
                hsh[rf * 16 + g * 4 + r][w * 64 + nf * 16 + c16] = f2bf(fmaxf(acc1[rf][nf][r] + bb, 0.f));
    }
    __syncthreads();

    // ---- layer 2 ----
    f32x4 acc2[2][2] = {};
    #pragma unroll
    for (int ks = 0; ks < 8; ++ks) {
        bf16x8 a0 = *(const bf16x8*)(&hsh[c16][ks * 32 + g * 8]);
        bf16x8 a1 = *(const bf16x8*)(&hsh[16 + c16][ks * 32 + g * 8]);
        #pragma unroll
        for (int nf = 0; nf < 2; ++nf) {
            int n = w * 32 + nf * 16 + c16;
            bf16x8 b = *(const bf16x8*)(w2b + (size_t)n * 256 + ks * 32 + g * 8);
            acc2[0][nf] = __builtin_amdgcn_mfma_f32_16x16x32_bf16(a0, b, acc2[0][nf], 0, 0, 0);
            acc2[1][nf] = __builtin_amdgcn_mfma_f32_16x16x32_bf16(a1, b, acc2[1][nf], 0, 0, 0);
        }
    }

    // ---- store z + fused BN partials ----
    #pragma unroll
    for (int nf = 0; nf < 2; ++nf) {
        int col = w * 32 + nf * 16 + c16;
        float bb = b2[col];
        float s = 0.f, ss = 0.f;
        #pragma unroll
        for (int rf = 0; rf < 2; ++rf)
            #pragma unroll
            for (int r = 0; r < 4; ++r) {
                float v = acc2[rf][nf][r] + bb;
                z[(size_t)(r0 + rf * 16 + g * 4 + r) * D + col] = f2bf(v);
                s += v; ss += v * v;
            }
        s  += __shfl_xor(s, 16);  s  += __shfl_xor(s, 32);
        ss += __shfl_xor(ss, 16); ss += __shfl_xor(ss, 32);
        if (g == 0) {
            part_s [((size_t)tensor * 256 + blk) * D + col] = s;
            part_ss[((size_t)tensor * 256 + blk) * D + col] = ss;
        }
    }
}

// ---------------- BN reduce ----------------
__global__ __launch_bounds__(256) void bn_reduce_kernel(
    const float* __restrict__ part_s, const float* __restrict__ part_ss,
    const float* __restrict__ gamma,
    float* __restrict__ mu, float* __restrict__ sc)
{
    const int t = threadIdx.x;
    const int tensor = blockIdx.x >> 7;
    const int col = blockIdx.x & 127;
    float s  = part_s [((size_t)tensor * 256 + t) * D + col];
    float ss = part_ss[((size_t)tensor * 256 + t) * D + col];
    #pragma unroll
    for (int m = 32; m; m >>= 1) { s += __shfl_xor(s, m); ss += __shfl_xor(ss, m); }
    __shared__ float rs[4], rss[4];
    if ((t & 63) == 0) { rs[t >> 6] = s; rss[t >> 6] = ss; }
    __syncthreads();
    if (t == 0) {
        float S = rs[0] + rs[1] + rs[2] + rs[3];
        float SS = rss[0] + rss[1] + rss[2] + rss[3];
        float m = S / (float)N_TOT;
        float var = SS / (float)N_TOT - m * m;
        mu[tensor * D + col] = m;
        sc[tensor * D + col] = gamma[col] * rsqrtf(var + 1e-5f);
    }
}

// ---------------- BN apply + L2 normalize (2 rows/wave, ushort4/lane) ----------------
// grid 2048: block -> 8 rows of the 16384 (tensor-major) rows.
__global__ __launch_bounds__(256) void bn_l2_kernel(
    unsigned short* __restrict__ z1, unsigned short* __restrict__ z2,
    const float* __restrict__ mu, const float* __restrict__ sc,
    const float* __restrict__ beta)
{
    const int t = threadIdx.x;
    const int wv = t >> 6;
    const int lane = t & 63;
    const int rw = lane >> 5;
    const int cl = lane & 31;            // 32 lanes x 4 cols
    const int grow = blockIdx.x * 8 + wv * 2 + rw;
    const int tensor = grow >> 13;
    const int row = grow & (N_TOT - 1);

    unsigned short* __restrict__ yr = (tensor ? z2 : z1) + (size_t)row * D + cl * 4;
    float4 m4 = *(const float4*)(mu + tensor * D + cl * 4);
    float4 s4 = *(const float4*)(sc + tensor * D + cl * 4);
    float4 b4 = *(const float4*)(beta + cl * 4);
    ushort4 v = *(const ushort4*)yr;
    float v0 = (bf2f(v.x) - m4.x) * s4.x + b4.x;
    float v1 = (bf2f(v.y) - m4.y) * s4.y + b4.y;
    float v2 = (bf2f(v.z) - m4.z) * s4.z + b4.z;
    float v3 = (bf2f(v.w) - m4.w) * s4.w + b4.w;
    float ssq = v0 * v0 + v1 * v1 + v2 * v2 + v3 * v3;
    #pragma unroll
    for (int m = 16; m; m >>= 1) ssq += __shfl_xor(ssq, m);   // stays in 32-group
    float rn = rsqrtf(ssq);
    if (tensor == 0) rn *= LOG2E;   // pre-scale z1 so loss exp = exp2
    ushort4 o;
    o.x = f2bf(v0 * rn); o.y = f2bf(v1 * rn);
    o.z = f2bf(v2 * rn); o.w = f2bf(v3 * rn);
    *(ushort4*)yr = o;
}

// ---------------- merged loss kernel: diag paths (bid<272) + MFMA off-diag ----------------
// MFMA blocks (bid>=272): 960 = 15 chunk-slots x 32 row-blocks x 2 col-halves.
// Block = 256 rows x 256 cols (half chunk, 4 x 64-col tiles). Wave w owns 64
// rows (rf=0..3): each ds_read_b128 feeds 4 MFMAs. Off-diag mask = 2 id cmps.
// den_part slot = (chunk*2+half) -> no cross-block races.
__global__ __launch_bounds__(256, 2) void loss_all_kernel(
    const short* __restrict__ z1, const short* __restrict__ z2,
    const int* __restrict__ ids,
    float* __restrict__ posv, float* __restrict__ dden,
    float* __restrict__ den_part)
{
    const int t = threadIdx.x;
    const int bid = blockIdx.x;

    if (bid < 256) {
        // pos terms + diag/next exps per row
        const int row = bid * 32 + (t >> 3);
        const int le = t & 7;
        const short* ap = z1 + (size_t)row * D + le * 16;
        const short* bp = z2 + (size_t)row * D + le * 16;
        const short* cp = z2 + (size_t)((row + 1) & (N_TOT - 1)) * D + le * 16;
        bf16x8 a0 = *(const bf16x8*)ap, a1 = *(const bf16x8*)(ap + 8);
        float s1 = dot8(a0, *(const bf16x8*)bp) + dot8(a1, *(const bf16x8*)(bp + 8));
        float s2 = dot8(a0, *(const bf16x8*)cp) + dot8(a1, *(const bf16x8*)(cp + 8));
        #pragma unroll
        for (int m = 1; m < 8; m <<= 1) { s1 += __shfl_xor(s1, m); s2 += __shfl_xor(s2, m); }
        if (le == 0) {
            bool two = (row & (SEQ_L - 1)) != (SEQ_L - 1);
            if (two) {
                posv[row] = (s1 + s2) * LN2;
                dden[row] = exp2f(s1) + exp2f(s2);
            } else {
                posv[row] = s1 * LN2;
            }
        }
        return;
    }
    if (bid < NDIAG) {
        // seq-end rows: full masked 512-col sum over own seq chunk
        __shared__ float red[4];
        const int sr = bid - 256;
        const int i = sr * SEQ_L + (SEQ_L - 1);
        const int jbase = sr * SEQ_L;
        const int idi_ = ids[i];
        float acc = 0.f;
        #pragma unroll
        for (int c = 0; c < 2; ++c) {
            int j = jbase + t * 2 + c;
            float s = 0.f;
            for (int k = 0; k < 16; ++k) {
                bf16x8 va = *(const bf16x8*)(z1 + (size_t)i * D + k * 8);
                bf16x8 vb = *(const bf16x8*)(z2 + (size_t)j * D + k * 8);
                s += dot8(va, vb);
            }
            bool m = (ids[j] != idi_) | (j == i);
            acc += m ? exp2f(s) : 0.f;
        }
        #pragma unroll
        for (int m = 32; m; m >>= 1) acc += __shfl_xor(acc, m);
        if ((t & 63) == 0) red[t >> 6] = acc;
        __syncthreads();
        if (t == 0) dden[i] = red[0] + red[1] + red[2] + red[3];
        return;
    }

    // ---------------- MFMA path ----------------
    const int bidm = bid - NDIAG;
    const int w    = t >> 6;
    const int lane = t & 63;
    const int g    = lane >> 4;
    const int c16  = lane & 15;

    const int c15  = bidm % 15;
    const int rbh  = bidm / 15;               // 0..63
    const int rbi  = rbh >> 1;                // 0..31
    const int half = rbh & 1;
    const int rb   = rbi * 256;
    const int seqb = rb >> 9;
    const int chunk = c15 + (c15 >= seqb);    // skip diagonal chunk
    const int jbase = chunk * CHUNK + half * 256;

    const int i_wb = rb + w * 64;

    __shared__ __align__(16) unsigned char z2s[2][64 * 256];  // 2 x 16KB

    const int srow = t >> 2;
    const int sq   = t & 3;
    const int wxor = (srow & 7) << 4;
    const int rxor = (c16 & 7) << 4;

    // A fragments: 4 row-frags x 4 k-steps (verified pattern)
    bf16x8 af[4][4];
    #pragma unroll
    for (int rf = 0; rf < 4; ++rf)
        #pragma unroll
        for (int ks = 0; ks < 4; ++ks)
            af[rf][ks] = *(const bf16x8*)(z1 + (size_t)(i_wb + rf * 16 + c16) * D + ks * 32 + g * 8);

    // row metadata: idi + sentinel-folded idn
    int idi[4][4], idn_s[4][4];
    #pragma unroll
    for (int rf = 0; rf < 4; ++rf)
        #pragma unroll
        for (int r = 0; r < 4; ++r) {
            int i = i_wb + rf * 16 + g * 4 + r;
            idi[rf][r] = ids[i];
            bool tw = ((i & (SEQ_L - 1)) != (SEQ_L - 1));
            idn_s[rf][r] = tw ? ids[(i + 1) & (N_TOT - 1)] : idi[rf][r];
        }

    // prologue: stage tile 0
    #pragma unroll
    for (int it = 0; it < 4; ++it) {
        bf16x8 v = *(const bf16x8*)(z2 + (size_t)(jbase + srow) * D + sq * 8 + it * 32);
        *(bf16x8*)&z2s[0][srow * 256 + ((sq * 16 + it * 64) ^ wxor)] = v;
    }
    __syncthreads();

    float den[4][4] = {};
    int cbuf = 0;

    #pragma unroll 1
    for (int jt = 0; jt < NJT_H; ++jt) {
        const int cb = jbase + jt * 64;

        // stage next tile into regs (T14 issue-early)
        bf16x8 stg[4];
        if (jt + 1 < NJT_H) {
            #pragma unroll
            for (int it = 0; it < 4; ++it)
                stg[it] = *(const bf16x8*)(z2 + (size_t)(cb + 64 + srow) * D + sq * 8 + it * 32);
        }

        int idj[4];
        #pragma unroll
        for (int nf = 0; nf < 4; ++nf) idj[nf] = ids[cb + nf * 16 + c16];

        // MFMA: one ds_read_b128 feeds 4 MFMAs (rf)
        f32x4 acc[4][4] = {};
        #pragma unroll
        for (int ks = 0; ks < 4; ++ks)
            #pragma unroll
            for (int nf = 0; nf < 4; ++nf) {
                bf16x8 b = *(const bf16x8*)&z2s[cbuf][(nf * 16 + c16) * 256 + ((ks * 64 + g * 16) ^ rxor)];
                #pragma unroll
                for (int rf = 0; rf < 4; ++rf)
                    acc[rf][nf] = __builtin_amdgcn_mfma_f32_16x16x32_bf16(af[rf][ks], b, acc[rf][nf], 0, 0, 0);
            }

        // write next buffer, then one barrier per jt
        if (jt + 1 < NJT_H) {
            #pragma unroll
            for (int it = 0; it < 4; ++it)
                *(bf16x8*)&z2s[cbuf ^ 1][srow * 256 + ((sq * 16 + it * 64) ^ wxor)] = stg[it];
        }
        __syncthreads();

        // post-barrier epilogue: masked exp2 accumulate
        #pragma unroll
        for (int rf = 0; rf < 4; ++rf)
            #pragma unroll
            for (int nf = 0; nf < 4; ++nf)
                #pragma unroll
                for (int r = 0; r < 4; ++r) {
                    float e = exp2f(acc[rf][nf][r]);
                    bool m = (idj[nf] != idi[rf][r]) & (idj[nf] != idn_s[rf][r]);
                    den[rf][r] += m ? e : 0.f;
                }
        cbuf ^= 1;
    }

    // 16-lane column reduce; single writer per (chunk-half, row)
    #pragma unroll
    for (int rf = 0; rf < 4; ++rf)
        #pragma unroll
        for (int r = 0; r < 4; ++r) {
            float dsum = den[rf][r];
            dsum += __shfl_xor(dsum, 1);
            dsum += __shfl_xor(dsum, 2);
            dsum += __shfl_xor(dsum, 4);
            dsum += __shfl_xor(dsum, 8);
            if (c16 == 0)
                den_part[(chunk * 2 + half) * N_TOT + i_wb + rf * 16 + g * 4 + r] = dsum;
        }
}

// ---------------- combine: den = dden + off-diag halves; loss scalar ----------------
__global__ __launch_bounds__(1024) void loss_finish_kernel(
    const float* __restrict__ den_part, const float* __restrict__ posv,
    const float* __restrict__ dden, float* __restrict__ out)
{
    const int t = threadIdx.x;
    float v = 0.f;
    for (int k = 0; k < N_TOT / 1024; ++k) {
        int row = t + k * 1024;
        int seqb = row >> 9;
        float den = dden[row];
        #pragma unroll
        for (int q = 0; q < 2 * NCHUNK; ++q)
            if ((q >> 1) != seqb) den += den_part[q * N_TOT + row];
        bool two = ((row & (SEQ_L - 1)) != (SEQ_L - 1));
        float npos = two ? 2.f : 1.f;
        v += -(posv[row] - logf(den)) / npos;
    }
    #pragma unroll
    for (int m = 32; m; m >>= 1) v += __shfl_xor(v, m);
    __shared__ float red[16];
    if ((t & 63) == 0) red[t >> 6] = v;
    __syncthreads();
    if (t == 0) {
        float tot = 0.f;
        #pragma unroll
        for (int i = 0; i < 16; ++i) tot += red[i];
        out[0] = tot / (float)N_TOT;
    }
}

extern "C" void kernel_launch(void* const* d_in, const int* in_sizes, int n_in,
                              void* d_out, int out_size, void* d_ws, size_t ws_size,
                              hipStream_t stream)
{
    const int*   ids   = (const int*)d_in[0];
    const float* x1    = (const float*)d_in[2];
    const float* x2    = (const float*)d_in[3];
    const float* w1    = (const float*)d_in[4];
    const float* b1    = (const float*)d_in[5];
    const float* w2    = (const float*)d_in[6];
    const float* b2    = (const float*)d_in[7];
    const float* gamma = (const float*)d_in[8];
    const float* beta  = (const float*)d_in[9];

    char* ws = (char*)d_ws;
    unsigned short* z1b = (unsigned short*)ws;                          // 2MB
    unsigned short* z2b = (unsigned short*)(ws + (2u << 20));           // 2MB
    float* part_s  = (float*)(ws + (4u << 20));                         // 256KB
    float* part_ss = part_s + 2 * 256 * D;                              // 256KB
    float* mu      = part_ss + 2 * 256 * D;
    float* sc      = mu + 2 * D;
    float* den_part = sc + 2 * D;                                       // 32*N = 1MB
    float* posv    = den_part + 2 * NCHUNK * N_TOT;                     // 32KB
    float* dden    = posv + N_TOT;                                      // 32KB
    unsigned short* w1b = (unsigned short*)(dden + N_TOT);              // 64KB
    unsigned short* w2b = w1b + 256 * D;                                // 64KB

    convert_w_kernel<<<64, 256, 0, stream>>>(w1, w2, w1b, w2b);
    mlp_mfma_kernel<<<512, 256, 0, stream>>>(x1, x2, w1b, b1, w2b, b2,
                                             z1b, z2b, part_s, part_ss);
    bn_reduce_kernel<<<256, 256, 0, stream>>>(part_s, part_ss, gamma, mu, sc);
    bn_l2_kernel<<<2048, 256, 0, stream>>>(z1b, z2b, mu, sc, beta);
    loss_all_kernel<<<NDIAG + 960, 256, 0, stream>>>((const short*)z1b, (const short*)z2b,
                                                     ids, posv, dden, den_part);
    loss_finish_kernel<<<1, 1024, 0, stream>>>(den_part, posv, dden, (float*)d_out);
}

// Round 14
// 86.879 us; speedup vs baseline: 1.6528x; 1.6528x over previous
//
#include <hip/hip_runtime.h>

#define N_TOT 8192
#define SEQ_L 512
#define D 128
#define NCHUNK 16
#define CHUNK (N_TOT / NCHUNK)   // 512 cols per j-chunk == one seq block
#define NJT_H 4                  // 4 x 64-col tiles per half-chunk
#define NDIAG 272                // 256 pos-blocks + 16 seq-end blocks
#define LOG2E 1.4426950408889634f
#define LN2   0.6931471805599453f

using bf16x8  = __attribute__((ext_vector_type(8))) short;
using f32x4   = __attribute__((ext_vector_type(4))) float;

static __device__ __forceinline__ unsigned short f2bf(float f) {
    unsigned int u = __float_as_uint(f);
    u = (u + 0x7FFFu + ((u >> 16) & 1u)) >> 16;
    return (unsigned short)u;
}
static __device__ __forceinline__ float bf2f(unsigned short h) {
    return __uint_as_float(((unsigned int)h) << 16);
}
static __device__ __forceinline__ float dot8(bf16x8 a, bf16x8 b) {
    float s = 0.f;
    #pragma unroll
    for (int k = 0; k < 8; ++k)
        s = fmaf(bf2f((unsigned short)a[k]), bf2f((unsigned short)b[k]), s);
    return s;
}

// ---------------- one-shot: convert w1/w2 to bf16 ----------------
__global__ __launch_bounds__(256) void convert_w_kernel(
    const float* __restrict__ w1, const float* __restrict__ w2,
    unsigned short* __restrict__ w1b, unsigned short* __restrict__ w2b)
{
    int idx = blockIdx.x * 256 + threadIdx.x;
    const float* src = (idx < 8192) ? w1 : w2;
    unsigned short* dst = (idx < 8192) ? w1b : w2b;
    int off = ((idx < 8192) ? idx : idx - 8192) * 4;
    float4 v = *(const float4*)(src + off);
    ushort4 o;
    o.x = f2bf(v.x); o.y = f2bf(v.y); o.z = f2bf(v.z); o.w = f2bf(v.w);
    *(ushort4*)(dst + off) = o;
}

// ---------------- MFMA MLP (32 rows/block) + fused BN column partials ----------------
__global__ __launch_bounds__(256) void mlp_mfma_kernel(
    const float* __restrict__ x1, const float* __restrict__ x2,
    const unsigned short* __restrict__ w1b, const float* __restrict__ b1,
    const unsigned short* __restrict__ w2b, const float* __restrict__ b2,
    unsigned short* __restrict__ z1, unsigned short* __restrict__ z2,
    float* __restrict__ part_s, float* __restrict__ part_ss)
{
    __shared__ unsigned short hsh[32][264];
    const int t = threadIdx.x;
    const int w = t >> 6;
    const int lane = t & 63;
    const int g = lane >> 4;
    const int c16 = lane & 15;
    const int tensor = blockIdx.x >> 8;
    const int blk = blockIdx.x & 255;
    const int r0 = blk * 32;
    const float* __restrict__ x = tensor ? x2 : x1;
    unsigned short* __restrict__ z = tensor ? z2 : z1;

    // ---- layer 1 ----
    bf16x8 af[2][4];
    #pragma unroll
    for (int rf = 0; rf < 2; ++rf)
        #pragma unroll
        for (int ks = 0; ks < 4; ++ks) {
            const float* xp = x + (size_t)(r0 + rf * 16 + c16) * D + ks * 32 + g * 8;
            float4 u0 = *(const float4*)xp;
            float4 u1 = *(const float4*)(xp + 4);
            bf16x8 a;
            a[0] = f2bf(u0.x); a[1] = f2bf(u0.y); a[2] = f2bf(u0.z); a[3] = f2bf(u0.w);
            a[4] = f2bf(u1.x); a[5] = f2bf(u1.y); a[6] = f2bf(u1.z); a[7] = f2bf(u1.w);
            af[rf][ks] = a;
        }
    f32x4 acc1[2][4] = {};
    #pragma unroll
    for (int ks = 0; ks < 4; ++ks)
        #pragma unroll
        for (int nf = 0; nf < 4; ++nf) {
            int n = w * 64 + nf * 16 + c16;
            bf16x8 b = *(const bf16x8*)(w1b + (size_t)n * D + ks * 32 + g * 8);
            #pragma unroll
            for (int rf = 0; rf < 2; ++rf)
                acc1[rf][nf] = __builtin_amdgcn_mfma_f32_16x16x32_bf16(af[rf][ks], b, acc1[rf][nf], 0, 0, 0);
        }
    #pragma unroll
    for (int nf = 0; nf < 4; ++nf) {
        float bb = b1[w * 64 + nf * 16 + c16];
        #pragma unroll
        for (int rf = 0; rf < 2; ++rf)
            #pragma unroll
            for (int r = 0; r < 4; ++r)
                hsh[rf * 16 + g * 4 + r][w * 64 + nf * 16 + c16] = f2bf(fmaxf(acc1[rf][nf][r] + bb, 0.f));
    }
    __syncthreads();

    // ---- layer 2 ----
    f32x4 acc2[2][2] = {};
    #pragma unroll
    for (int ks = 0; ks < 8; ++ks) {
        bf16x8 a0 = *(const bf16x8*)(&hsh[c16][ks * 32 + g * 8]);
        bf16x8 a1 = *(const bf16x8*)(&hsh[16 + c16][ks * 32 + g * 8]);
        #pragma unroll
        for (int nf = 0; nf < 2; ++nf) {
            int n = w * 32 + nf * 16 + c16;
            bf16x8 b = *(const bf16x8*)(w2b + (size_t)n * 256 + ks * 32 + g * 8);
            acc2[0][nf] = __builtin_amdgcn_mfma_f32_16x16x32_bf16(a0, b, acc2[0][nf], 0, 0, 0);
            acc2[1][nf] = __builtin_amdgcn_mfma_f32_16x16x32_bf16(a1, b, acc2[1][nf], 0, 0, 0);
        }
    }

    // ---- store z + fused BN partials ----
    #pragma unroll
    for (int nf = 0; nf < 2; ++nf) {
        int col = w * 32 + nf * 16 + c16;
        float bb = b2[col];
        float s = 0.f, ss = 0.f;
        #pragma unroll
        for (int rf = 0; rf < 2; ++rf)
            #pragma unroll
            for (int r = 0; r < 4; ++r) {
                float v = acc2[rf][nf][r] + bb;
                z[(size_t)(r0 + rf * 16 + g * 4 + r) * D + col] = f2bf(v);
                s += v; ss += v * v;
            }
        s  += __shfl_xor(s, 16);  s  += __shfl_xor(s, 32);
        ss += __shfl_xor(ss, 16); ss += __shfl_xor(ss, 32);
        if (g == 0) {
            part_s [((size_t)tensor * 256 + blk) * D + col] = s;
            part_ss[((size_t)tensor * 256 + blk) * D + col] = ss;
        }
    }
}

// ---------------- BN reduce ----------------
__global__ __launch_bounds__(256) void bn_reduce_kernel(
    const float* __restrict__ part_s, const float* __restrict__ part_ss,
    const float* __restrict__ gamma,
    float* __restrict__ mu, float* __restrict__ sc)
{
    const int t = threadIdx.x;
    const int tensor = blockIdx.x >> 7;
    const int col = blockIdx.x & 127;
    float s  = part_s [((size_t)tensor * 256 + t) * D + col];
    float ss = part_ss[((size_t)tensor * 256 + t) * D + col];
    #pragma unroll
    for (int m = 32; m; m >>= 1) { s += __shfl_xor(s, m); ss += __shfl_xor(ss, m); }
    __shared__ float rs[4], rss[4];
    if ((t & 63) == 0) { rs[t >> 6] = s; rss[t >> 6] = ss; }
    __syncthreads();
    if (t == 0) {
        float S = rs[0] + rs[1] + rs[2] + rs[3];
        float SS = rss[0] + rss[1] + rss[2] + rss[3];
        float m = S / (float)N_TOT;
        float var = SS / (float)N_TOT - m * m;
        mu[tensor * D + col] = m;
        sc[tensor * D + col] = gamma[col] * rsqrtf(var + 1e-5f);
    }
}

// ---------------- BN apply + L2 normalize (2 rows/wave, ushort4/lane) ----------------
__global__ __launch_bounds__(256) void bn_l2_kernel(
    unsigned short* __restrict__ z1, unsigned short* __restrict__ z2,
    const float* __restrict__ mu, const float* __restrict__ sc,
    const float* __restrict__ beta)
{
    const int t = threadIdx.x;
    const int wv = t >> 6;
    const int lane = t & 63;
    const int rw = lane >> 5;
    const int cl = lane & 31;            // 32 lanes x 4 cols
    const int grow = blockIdx.x * 8 + wv * 2 + rw;
    const int tensor = grow >> 13;
    const int row = grow & (N_TOT - 1);

    unsigned short* __restrict__ yr = (tensor ? z2 : z1) + (size_t)row * D + cl * 4;
    float4 m4 = *(const float4*)(mu + tensor * D + cl * 4);
    float4 s4 = *(const float4*)(sc + tensor * D + cl * 4);
    float4 b4 = *(const float4*)(beta + cl * 4);
    ushort4 v = *(const ushort4*)yr;
    float v0 = (bf2f(v.x) - m4.x) * s4.x + b4.x;
    float v1 = (bf2f(v.y) - m4.y) * s4.y + b4.y;
    float v2 = (bf2f(v.z) - m4.z) * s4.z + b4.z;
    float v3 = (bf2f(v.w) - m4.w) * s4.w + b4.w;
    float ssq = v0 * v0 + v1 * v1 + v2 * v2 + v3 * v3;
    #pragma unroll
    for (int m = 16; m; m >>= 1) ssq += __shfl_xor(ssq, m);   // stays in 32-group
    float rn = rsqrtf(ssq);
    if (tensor == 0) rn *= LOG2E;   // pre-scale z1 so loss exp = exp2
    ushort4 o;
    o.x = f2bf(v0 * rn); o.y = f2bf(v1 * rn);
    o.z = f2bf(v2 * rn); o.w = f2bf(v3 * rn);
    *(ushort4*)yr = o;
}

// ---------------- merged loss kernel: diag paths (bid<272) + MFMA off-diag ----------------
__global__ __launch_bounds__(256, 2) void loss_all_kernel(
    const short* __restrict__ z1, const short* __restrict__ z2,
    const int* __restrict__ ids,
    float* __restrict__ posv, float* __restrict__ dden,
    float* __restrict__ den_part)
{
    const int t = threadIdx.x;
    const int bid = blockIdx.x;

    if (bid < 256) {
        // pos terms + diag/next exps per row
        const int row = bid * 32 + (t >> 3);
        const int le = t & 7;
        const short* ap = z1 + (size_t)row * D + le * 16;
        const short* bp = z2 + (size_t)row * D + le * 16;
        const short* cp = z2 + (size_t)((row + 1) & (N_TOT - 1)) * D + le * 16;
        bf16x8 a0 = *(const bf16x8*)ap, a1 = *(const bf16x8*)(ap + 8);
        float s1 = dot8(a0, *(const bf16x8*)bp) + dot8(a1, *(const bf16x8*)(bp + 8));
        float s2 = dot8(a0, *(const bf16x8*)cp) + dot8(a1, *(const bf16x8*)(cp + 8));
        #pragma unroll
        for (int m = 1; m < 8; m <<= 1) { s1 += __shfl_xor(s1, m); s2 += __shfl_xor(s2, m); }
        if (le == 0) {
            bool two = (row & (SEQ_L - 1)) != (SEQ_L - 1);
            if (two) {
                posv[row] = (s1 + s2) * LN2;
                dden[row] = exp2f(s1) + exp2f(s2);
            } else {
                posv[row] = s1 * LN2;
            }
        }
        return;
    }
    if (bid < NDIAG) {
        // seq-end rows: full masked 512-col sum over own seq chunk
        __shared__ float red[4];
        const int sr = bid - 256;
        const int i = sr * SEQ_L + (SEQ_L - 1);
        const int jbase = sr * SEQ_L;
        const int idi_ = ids[i];
        float acc = 0.f;
        #pragma unroll
        for (int c = 0; c < 2; ++c) {
            int j = jbase + t * 2 + c;
            float s = 0.f;
            for (int k = 0; k < 16; ++k) {
                bf16x8 va = *(const bf16x8*)(z1 + (size_t)i * D + k * 8);
                bf16x8 vb = *(const bf16x8*)(z2 + (size_t)j * D + k * 8);
                s += dot8(va, vb);
            }
            bool m = (ids[j] != idi_) | (j == i);
            acc += m ? exp2f(s) : 0.f;
        }
        #pragma unroll
        for (int m = 32; m; m >>= 1) acc += __shfl_xor(acc, m);
        if ((t & 63) == 0) red[t >> 6] = acc;
        __syncthreads();
        if (t == 0) dden[i] = red[0] + red[1] + red[2] + red[3];
        return;
    }

    // ---------------- MFMA path ----------------
    const int bidm = bid - NDIAG;
    const int w    = t >> 6;
    const int lane = t & 63;
    const int g    = lane >> 4;
    const int c16  = lane & 15;

    const int c15  = bidm % 15;
    const int rbh  = bidm / 15;               // 0..63
    const int rbi  = rbh >> 1;                // 0..31
    const int half = rbh & 1;
    const int rb   = rbi * 256;
    const int seqb = rb >> 9;
    const int chunk = c15 + (c15 >= seqb);    // skip diagonal chunk
    const int jbase = chunk * CHUNK + half * 256;

    const int i_wb = rb + w * 64;

    __shared__ __align__(16) unsigned char z2s[2][64 * 256];  // 2 x 16KB

    const int srow = t >> 2;
    const int sq   = t & 3;
    const int wxor = (srow & 7) << 4;
    const int rxor = (c16 & 7) << 4;

    // A fragments: 4 row-frags x 4 k-steps (verified pattern)
    bf16x8 af[4][4];
    #pragma unroll
    for (int rf = 0; rf < 4; ++rf)
        #pragma unroll
        for (int ks = 0; ks < 4; ++ks)
            af[rf][ks] = *(const bf16x8*)(z1 + (size_t)(i_wb + rf * 16 + c16) * D + ks * 32 + g * 8);

    // row metadata: idi + sentinel-folded idn
    int idi[4][4], idn_s[4][4];
    #pragma unroll
    for (int rf = 0; rf < 4; ++rf)
        #pragma unroll
        for (int r = 0; r < 4; ++r) {
            int i = i_wb + rf * 16 + g * 4 + r;
            idi[rf][r] = ids[i];
            bool tw = ((i & (SEQ_L - 1)) != (SEQ_L - 1));
            idn_s[rf][r] = tw ? ids[(i + 1) & (N_TOT - 1)] : idi[rf][r];
        }

    // prologue: stage tile 0
    #pragma unroll
    for (int it = 0; it < 4; ++it) {
        bf16x8 v = *(const bf16x8*)(z2 + (size_t)(jbase + srow) * D + sq * 8 + it * 32);
        *(bf16x8*)&z2s[0][srow * 256 + ((sq * 16 + it * 64) ^ wxor)] = v;
    }
    __syncthreads();

    float den[4][4] = {};
    int cbuf = 0;

    #pragma unroll 1
    for (int jt = 0; jt < NJT_H; ++jt) {
        const int cb = jbase + jt * 64;

        // stage next tile into regs (T14 issue-early)
        bf16x8 stg[4];
        if (jt + 1 < NJT_H) {
            #pragma unroll
            for (int it = 0; it < 4; ++it)
                stg[it] = *(const bf16x8*)(z2 + (size_t)(cb + 64 + srow) * D + sq * 8 + it * 32);
        }

        int idj[4];
        #pragma unroll
        for (int nf = 0; nf < 4; ++nf) idj[nf] = ids[cb + nf * 16 + c16];

        // MFMA: one ds_read_b128 feeds 4 MFMAs (rf)
        f32x4 acc[4][4] = {};
        #pragma unroll
        for (int ks = 0; ks < 4; ++ks)
            #pragma unroll
            for (int nf = 0; nf < 4; ++nf) {
                bf16x8 b = *(const bf16x8*)&z2s[cbuf][(nf * 16 + c16) * 256 + ((ks * 64 + g * 16) ^ rxor)];
                #pragma unroll
                for (int rf = 0; rf < 4; ++rf)
                    acc[rf][nf] = __builtin_amdgcn_mfma_f32_16x16x32_bf16(af[rf][ks], b, acc[rf][nf], 0, 0, 0);
            }

        // write next buffer, then one barrier per jt
        if (jt + 1 < NJT_H) {
            #pragma unroll
            for (int it = 0; it < 4; ++it)
                *(bf16x8*)&z2s[cbuf ^ 1][srow * 256 + ((sq * 16 + it * 64) ^ wxor)] = stg[it];
        }
        __syncthreads();

        // post-barrier epilogue: masked exp2 accumulate
        #pragma unroll
        for (int rf = 0; rf < 4; ++rf)
            #pragma unroll
            for (int nf = 0; nf < 4; ++nf)
                #pragma unroll
                for (int r = 0; r < 4; ++r) {
                    float e = exp2f(acc[rf][nf][r]);
                    bool m = (idj[nf] != idi[rf][r]) & (idj[nf] != idn_s[rf][r]);
                    den[rf][r] += m ? e : 0.f;
                }
        cbuf ^= 1;
    }

    // 16-lane column reduce; single writer per (chunk-half, row)
    #pragma unroll
    for (int rf = 0; rf < 4; ++rf)
        #pragma unroll
        for (int r = 0; r < 4; ++r) {
            float dsum = den[rf][r];
            dsum += __shfl_xor(dsum, 1);
            dsum += __shfl_xor(dsum, 2);
            dsum += __shfl_xor(dsum, 4);
            dsum += __shfl_xor(dsum, 8);
            if (c16 == 0)
                den_part[(chunk * 2 + half) * N_TOT + i_wb + rf * 16 + g * 4 + r] = dsum;
        }
}

// ---------------- finish stage 1: per-row inner, 32 blocks (coalesced) ----------------
__global__ __launch_bounds__(256) void loss_finish1_kernel(
    const float* __restrict__ den_part, const float* __restrict__ posv,
    const float* __restrict__ dden, float* __restrict__ partial)
{
    const int t = threadIdx.x;
    const int row = blockIdx.x * 256 + t;
    const int seqb = row >> 9;
    float den = dden[row];
    #pragma unroll
    for (int q = 0; q < 2 * NCHUNK; ++q)
        if ((q >> 1) != seqb) den += den_part[q * N_TOT + row];
    bool two = ((row & (SEQ_L - 1)) != (SEQ_L - 1));
    float npos = two ? 2.f : 1.f;
    float v = -(posv[row] - logf(den)) / npos;

    #pragma unroll
    for (int m = 32; m; m >>= 1) v += __shfl_xor(v, m);
    __shared__ float red[4];
    if ((t & 63) == 0) red[t >> 6] = v;
    __syncthreads();
    if (t == 0) partial[blockIdx.x] = red[0] + red[1] + red[2] + red[3];
}

// ---------------- finish stage 2: sum 32 partials -> scalar ----------------
__global__ __launch_bounds__(64) void loss_finish2_kernel(
    const float* __restrict__ partial, float* __restrict__ out)
{
    const int t = threadIdx.x;
    float v = (t < 32) ? partial[t] : 0.f;
    #pragma unroll
    for (int m = 32; m; m >>= 1) v += __shfl_xor(v, m);
    if (t == 0) out[0] = v / (float)N_TOT;
}

extern "C" void kernel_launch(void* const* d_in, const int* in_sizes, int n_in,
                              void* d_out, int out_size, void* d_ws, size_t ws_size,
                              hipStream_t stream)
{
    const int*   ids   = (const int*)d_in[0];
    const float* x1    = (const float*)d_in[2];
    const float* x2    = (const float*)d_in[3];
    const float* w1    = (const float*)d_in[4];
    const float* b1    = (const float*)d_in[5];
    const float* w2    = (const float*)d_in[6];
    const float* b2    = (const float*)d_in[7];
    const float* gamma = (const float*)d_in[8];
    const float* beta  = (const float*)d_in[9];

    char* ws = (char*)d_ws;
    unsigned short* z1b = (unsigned short*)ws;                          // 2MB
    unsigned short* z2b = (unsigned short*)(ws + (2u << 20));           // 2MB
    float* part_s  = (float*)(ws + (4u << 20));                         // 256KB
    float* part_ss = part_s + 2 * 256 * D;                              // 256KB
    float* mu      = part_ss + 2 * 256 * D;
    float* sc      = mu + 2 * D;
    float* den_part = sc + 2 * D;                                       // 32*N = 1MB
    float* posv    = den_part + 2 * NCHUNK * N_TOT;                     // 32KB
    float* dden    = posv + N_TOT;                                      // 32KB
    float* partial = dden + N_TOT;                                      // 32 floats
    unsigned short* w1b = (unsigned short*)(partial + 64);              // 64KB
    unsigned short* w2b = w1b + 256 * D;                                // 64KB

    convert_w_kernel<<<64, 256, 0, stream>>>(w1, w2, w1b, w2b);
    mlp_mfma_kernel<<<512, 256, 0, stream>>>(x1, x2, w1b, b1, w2b, b2,
                                             z1b, z2b, part_s, part_ss);
    bn_reduce_kernel<<<256, 256, 0, stream>>>(part_s, part_ss, gamma, mu, sc);
    bn_l2_kernel<<<2048, 256, 0, stream>>>(z1b, z2b, mu, sc, beta);
    loss_all_kernel<<<NDIAG + 960, 256, 0, stream>>>((const short*)z1b, (const short*)z2b,
                                                     ids, posv, dden, den_part);
    loss_finish1_kernel<<<32, 256, 0, stream>>>(den_part, posv, dden, partial);
    loss_finish2_kernel<<<1, 64, 0, stream>>>(partial, (float*)d_out);
}